// Round 10
// baseline (413.641 us; speedup 1.0000x reference)
//
#include <hip/hip_runtime.h>

// out[e,i] = sum_j mat[e,i,j] v[e,j] + bias[e,i],  [mat|bias] = MLP(pos).reshape(32,33)
// Round-11: G-loop on mfma_f32_32x32x16 (was 16x16x32).
// r7-r9 established: occupancy is register-capped at 2 waves/SIMD (arch cap=256/arg2,
// AGPRs unused by compiler); MFMA pipe-busy (33us) == measured MfmaUtil * wall ->
// the wall is per-wave MFMA issue/dependency spacing. Fix: halve MFMA instruction
// count with the 32x32x16 shape (528 vs 1056 per wave, same FLOPs), halving chain
// count per FLOP. A 32-col tile == one j -> v-weight is a single v[e,j] per tile and
// b3 enters as the per-tile C-init b3[i*33+j] (weighted by the same v[e,j]; tile j=32
// has v=1 and covers the W3-bias col + b3[i*33+32]); the old b3 mini-GEMM dies.
// No launch_bounds: demand ~176 (af 64 + oa 32 + c 32 + bf 32 + misc); uncapped
// allocator cannot spill; 2 waves/SIMD is what we effectively get anyway.
//   C-layout 32x32 (m74/m101): col=lane&31, row=(reg&3)+8*(reg>>2)+4*(lane>>5)
//   A: row=l&31, k=(l>>5)*8+jj ; B: k=(l>>5)*8+jj, col=l&31 (per-shape convention)
// LDS = vt only (34320 B), prologue h1c/h2n overlaid as before.
// ws: b3t @0 (4224 B), Wg3 @4224 (270336 B), W2f @274560 (32768 B); total 307328 B.
// (G-loop j=32 iteration prefetches "tile 33" = first 8 KB of W2f region: in-bounds,
//  values unused.)

#define E_TOTAL 262144
#define EPB 256
#define NBLK (E_TOTAL / EPB)

typedef float f32x4  __attribute__((ext_vector_type(4)));
typedef float f32x16 __attribute__((ext_vector_type(16)));
typedef short s8v    __attribute__((ext_vector_type(8)));

__device__ __forceinline__ unsigned short f2bf(float x) {
  unsigned u = __float_as_uint(x);
  u += 0x7fffu + ((u >> 16) & 1u);
  return (unsigned short)(u >> 16);
}

// ---------------- prep: pack W2/W3/b3 ----------------
// Coalesced f32 reads, scattered bf16 writes.
// Wg3[((j*8+ks)*64 + lane)*8 + jj] = B-frag for 32x32x16: tile j (cols i=0..31 of
// W3-col index i*33+j), k = ks*16 + (lane>>5)*8 + jj, n = lane&31.
__global__ void prep_pack(const float* __restrict__ W2, const float* __restrict__ W3,
                          const float* __restrict__ b3,
                          float* __restrict__ b3t, unsigned short* __restrict__ Wg3,
                          unsigned short* __restrict__ W2f) {
  int idx = blockIdx.x * 256 + threadIdx.x;   // 528 blocks cover 135168
  if (idx < 135168) {
    // src: W3[k][c], c = i*33 + jc  (jc=32 -> W3 bias col, becomes tile 32)
    int k = idx / 1056, c = idx % 1056;
    int i = c / 33, jc = c % 33;
    int ks = k >> 4, hi = (k >> 3) & 1, jj = k & 7;
    int lane = hi * 32 + i;
    Wg3[((jc * 8 + ks) * 64 + lane) * 8 + jj] = f2bf(W3[idx]);
  }
  if (idx < 16384) {
    // W2f (16x16x32 B-frags for the prologue, unchanged layout)
    int k = idx >> 7, n = idx & 127;
    int ks = k >> 5, kr = k & 31;
    int nt = n >> 4, low = n & 15;
    int l = ((kr >> 3) << 4) + low;
    int jj = k & 7;
    W2f[((ks * 8 + nt) * 64 + l) * 8 + jj] = f2bf(W2[idx]);
  }
  if (idx < 1056) {
    // b3t[jc*32 + i] = b3[i*33 + jc]  (per-tile C-init values, f32)
    int i = idx / 33, jc = idx % 33;
    b3t[jc * 32 + i] = b3[idx];
  }
}

// ---------------- fused main kernel ----------------
// 256 threads (4 waves), 256 edges/block; wave w owns edges [B0+w*64, B0+w*64+64).
// LDS (overlapped phases):
//   prologue: h2n u16[64][136] @0 (17408), h1c u16[32][136] @17408 (8704)
//   G-loop:   vt f32[33][260] @0 (34320)
__global__ void fnn_fused(
    const float* __restrict__ pos_i, const float* __restrict__ pos_j,
    const float* __restrict__ vj, const float* __restrict__ W1,
    const float* __restrict__ b1, const float* __restrict__ b2,
    const unsigned short* __restrict__ W2f, const unsigned short* __restrict__ Wg3,
    const float* __restrict__ b3t,
    float* __restrict__ out) {
  __shared__ __attribute__((aligned(16))) char smem[34320];
  float* vt = (float*)smem;                                  // [33][260], G-loop phase
  unsigned short* h2n = (unsigned short*)smem;               // [64][136], prologue phase
  unsigned short* h1c = (unsigned short*)(smem + 17408);     // [32][136], prologue phase

  const int tid = threadIdx.x;
  const int w = tid >> 6, lane = tid & 63, q = lane >> 4, ln = lane & 15;
  const int hi = lane >> 5, i31 = lane & 31;
  const int B0 = blockIdx.x * EPB;

  // --- W1/b1 register slice: thread owns 8 hidden cols for stage 1 ---
  const int hh0 = (tid & 15) * 8;
  float w1r[4][8], b1r[8];
#pragma unroll
  for (int d = 0; d < 4; ++d)
#pragma unroll
    for (int u = 0; u < 8; ++u) w1r[d][u] = W1[d * 128 + hh0 + u];
#pragma unroll
  for (int u = 0; u < 8; ++u) b1r[u] = b1[hh0 + u];

  // --- stages 1+2 per quarter (64 edges), extract A-frags to registers ---
  // af[m][ks] = 32x32x16 A-frag: row = lane&31 (edge m*32+row), k = ks*16+(lane>>5)*8+jj
  s8v af[2][8];
  for (int qtr = 0; qtr < 4; ++qtr) {
    for (int cb = 0; cb < 2; ++cb) {
#pragma unroll
      for (int half = 0; half < 2; ++half) {
        int ee = (tid >> 4) + half * 16;
        int eg = B0 + qtr * 64 + cb * 32 + ee;
        float2 pi = *(const float2*)(pos_i + (size_t)eg * 2);
        float2 pj = *(const float2*)(pos_j + (size_t)eg * 2);
        s8v hv;
#pragma unroll
        for (int u = 0; u < 8; ++u) {
          float o = b1r[u] + pi.x * w1r[0][u] + pi.y * w1r[1][u] +
                    pj.x * w1r[2][u] + pj.y * w1r[3][u];
          hv[u] = (short)f2bf(fmaxf(o, 0.f));
        }
        *(s8v*)&h1c[ee * 136 + hh0] = hv;
      }
      __syncthreads();
#pragma unroll
      for (int s = 0; s < 4; ++s) {
        int tt = w * 4 + s, mt = tt >> 3, nt = tt & 7;
        f32x4 a4 = {0.f, 0.f, 0.f, 0.f};
#pragma unroll
        for (int ks = 0; ks < 4; ++ks) {
          s8v afr = *(const s8v*)&h1c[(mt * 16 + ln) * 136 + ks * 32 + q * 8];
          s8v bfr = *(const s8v*)(W2f + ((ks * 8 + nt) * 64 + lane) * 8);
          a4 = __builtin_amdgcn_mfma_f32_16x16x32_bf16(afr, bfr, a4, 0, 0, 0);
        }
        float b2v = b2[nt * 16 + ln];
        int eb = cb * 32 + mt * 16 + q * 4;
        int kc = nt * 16 + ln;
#pragma unroll
        for (int r = 0; r < 4; ++r)
          h2n[(eb + r) * 136 + kc] = f2bf(fmaxf(a4[r] + b2v, 0.f));
      }
      __syncthreads();
    }
    if (w == qtr) {
#pragma unroll
      for (int m = 0; m < 2; ++m)
#pragma unroll
        for (int ks = 0; ks < 8; ++ks)
          af[m][ks] = *(const s8v*)&h2n[(m * 32 + i31) * 136 + ks * 16 + hi * 8];
    }
    __syncthreads();   // last cross-wave dep: h2n reads drained before vt overwrite
  }

  // --- prime B tile 0 (two half-tile register buffers) while vt is being built ---
  s8v bfA[4], bfB[4];
#pragma unroll
  for (int t = 0; t < 4; ++t) bfA[t] = *(const s8v*)(Wg3 + ((0 * 8 + t) * 64 + lane) * 8);
#pragma unroll
  for (int t = 0; t < 4; ++t) bfB[t] = *(const s8v*)(Wg3 + ((0 * 8 + 4 + t) * 64 + lane) * 8);

  // --- build vt: vt[j][e] = v[e,j] (f32), row 32 = 1.0 (overwrites h1c/h2n region) ---
  // Wave w writes ONLY columns [w*64, w*64+64) and reads ONLY those columns in the
  // G-loop -> no cross-wave dependency -> NO barrier needed from here on.
  {
    const float* vrow = vj + (size_t)(B0 + tid) * 32;
#pragma unroll
    for (int j4 = 0; j4 < 8; ++j4) {
      float4 vv = *(const float4*)(vrow + j4 * 4);
      vt[(j4 * 4 + 0) * 260 + tid] = vv.x;
      vt[(j4 * 4 + 1) * 260 + tid] = vv.y;
      vt[(j4 * 4 + 2) * 260 + tid] = vv.z;
      vt[(j4 * 4 + 3) * 260 + tid] = vv.w;
    }
    vt[32 * 260 + tid] = 1.0f;
  }

  // --- G-loop: 33 j-tiles (32 cols each), zero barriers, half-tile ping-pong prefetch.
  //     Per tile: C-init = b3t broadcast; 16 MFMA (2 m-chains interleaved);
  //     epilogue oa += v[e,j] * C.
  f32x16 oa0, oa1;
#pragma unroll
  for (int r = 0; r < 16; ++r) { oa0[r] = 0.f; oa1[r] = 0.f; }

#pragma unroll 1
  for (int j = 0; j < 33; ++j) {
    float ci = b3t[j * 32 + i31];
    f32x16 c0, c1;
#pragma unroll
    for (int r = 0; r < 16; ++r) { c0[r] = ci; c1[r] = ci; }
#pragma unroll
    for (int ks = 0; ks < 4; ++ks) {
      c0 = __builtin_amdgcn_mfma_f32_32x32x16_bf16(af[0][ks], bfA[ks], c0, 0, 0, 0);
      c1 = __builtin_amdgcn_mfma_f32_32x32x16_bf16(af[1][ks], bfA[ks], c1, 0, 0, 0);
    }
#pragma unroll
    for (int t = 0; t < 4; ++t)   // prefetch next tile half-0 (j=32 -> W2f pad, unused)
      bfA[t] = *(const s8v*)(Wg3 + (((j + 1) * 8 + t) * 64 + lane) * 8);
#pragma unroll
    for (int ks = 0; ks < 4; ++ks) {
      c0 = __builtin_amdgcn_mfma_f32_32x32x16_bf16(af[0][4 + ks], bfB[ks], c0, 0, 0, 0);
      c1 = __builtin_amdgcn_mfma_f32_32x32x16_bf16(af[1][4 + ks], bfB[ks], c1, 0, 0, 0);
    }
#pragma unroll
    for (int t = 0; t < 4; ++t)   // prefetch next tile half-1
      bfB[t] = *(const s8v*)(Wg3 + (((j + 1) * 8 + 4 + t) * 64 + lane) * 8);

    // epilogue: edge row = (reg&3) + 8*(reg>>2) + 4*hi (+ m*32 + w*64)
    const float* vp = vt + j * 260 + w * 64 + 4 * hi;
#pragma unroll
    for (int g = 0; g < 4; ++g) {
      f32x4 vv = *(const f32x4*)(vp + 8 * g);
#pragma unroll
      for (int rr = 0; rr < 4; ++rr) oa0[4 * g + rr] += vv[rr] * c0[4 * g + rr];
    }
#pragma unroll
    for (int g = 0; g < 4; ++g) {
      f32x4 vv = *(const f32x4*)(vp + 32 + 8 * g);
#pragma unroll
      for (int rr = 0; rr < 4; ++rr) oa1[4 * g + rr] += vv[rr] * c1[4 * g + rr];
    }
  }

  // --- epilogue: out[e,i] f32; lanes 0..31 -> row e, lanes 32..63 -> row e+4 ---
#pragma unroll
  for (int g = 0; g < 4; ++g)
#pragma unroll
    for (int rr = 0; rr < 4; ++rr) {
      int e = B0 + w * 64 + 8 * g + 4 * hi + rr;
      out[(size_t)e * 32 + i31] = oa0[4 * g + rr];
    }
#pragma unroll
  for (int g = 0; g < 4; ++g)
#pragma unroll
    for (int rr = 0; rr < 4; ++rr) {
      int e = B0 + w * 64 + 32 + 8 * g + 4 * hi + rr;
      out[(size_t)e * 32 + i31] = oa1[4 * g + rr];
    }
}

extern "C" void kernel_launch(void* const* d_in, const int* in_sizes, int n_in,
                              void* d_out, int out_size, void* d_ws, size_t ws_size,
                              hipStream_t stream) {
  const float* pos_i = (const float*)d_in[0];
  const float* pos_j = (const float*)d_in[1];
  const float* vj    = (const float*)d_in[2];
  const float* W1    = (const float*)d_in[3];
  const float* b1    = (const float*)d_in[4];
  const float* W2    = (const float*)d_in[5];
  const float* b2    = (const float*)d_in[6];
  const float* W3    = (const float*)d_in[7];
  const float* b3    = (const float*)d_in[8];
  float* outp = (float*)d_out;

  float*          b3t = (float*)d_ws;                                   // 4224 B
  unsigned short* Wg3 = (unsigned short*)((char*)d_ws + 4224);          // 270336 B
  unsigned short* W2f = (unsigned short*)((char*)d_ws + 274560);        // 32768 B

  prep_pack<<<528, 256, 0, stream>>>(W2, W3, b3, b3t, Wg3, W2f);
  fnn_fused<<<NBLK, 256, 0, stream>>>(pos_i, pos_j, vj, W1, b1, b2, W2f, Wg3, b3t, outp);
}

// Round 11
// 243.719 us; speedup vs baseline: 1.6972x; 1.6972x over previous
//
#include <hip/hip_runtime.h>

// out[e,i] = sum_j mat[e,i,j] v[e,j] + bias[e,i],  [mat|bias] = MLP(pos).reshape(32,33)
// Round-12: r10 structure (32x32x16 G-loop) + __launch_bounds__(256).
// r10 failure was mechanical: NO launch_bounds -> hipcc assumes 1024-thread blocks ->
// 64-VGPR cap (VGPR_Count=64, SGPR=32, FETCH 941MB spill signature). With
// __launch_bounds__(256) the allocator gets the full 512/wave budget; demand ~176-200
// allocates cleanly -> 2 waves/SIMD, same effective residency as r7's best.
// This isolates the shape experiment: 528 32x32x16 MFMAs/wave (2 independent C-chains
// interleaved) vs r7's 1056 16x16x32 (4-deep chains) at equal FLOPs.
//   C-layout 32x32 (m74/m101): col=lane&31, row=(reg&3)+8*(reg>>2)+4*(lane>>5)
//   A: row=l&31, k=(l>>5)*8+jj ; B: k=(l>>5)*8+jj, col=l&31
//   b3 enters as per-tile C-init b3[i*33+j] (v-weighted by the same v[e,j]; tile 32
//   has v=1 and carries the W3-bias col + b3[i*33+32]).
// LDS = vt only (34320 B), prologue h1c/h2n overlaid as before.
// ws: b3t @0 (4224 B), Wg3 @4224 (270336 B), W2f @274560 (32768 B); total 307328 B.
// (G-loop j=32 prefetches "tile 33" = first 8 KB of W2f region: in-bounds, unused.)

#define E_TOTAL 262144
#define EPB 256
#define NBLK (E_TOTAL / EPB)

typedef float f32x4  __attribute__((ext_vector_type(4)));
typedef float f32x16 __attribute__((ext_vector_type(16)));
typedef short s8v    __attribute__((ext_vector_type(8)));

__device__ __forceinline__ unsigned short f2bf(float x) {
  unsigned u = __float_as_uint(x);
  u += 0x7fffu + ((u >> 16) & 1u);
  return (unsigned short)(u >> 16);
}

// ---------------- prep: pack W2/W3/b3 ----------------
// Coalesced f32 reads, scattered bf16 writes.
// Wg3[((j*8+ks)*64 + lane)*8 + jj] = B-frag for 32x32x16: tile j (cols i=0..31 of
// W3-col index i*33+j), k = ks*16 + (lane>>5)*8 + jj, n = lane&31.
__global__ void prep_pack(const float* __restrict__ W2, const float* __restrict__ W3,
                          const float* __restrict__ b3,
                          float* __restrict__ b3t, unsigned short* __restrict__ Wg3,
                          unsigned short* __restrict__ W2f) {
  int idx = blockIdx.x * 256 + threadIdx.x;   // 528 blocks cover 135168
  if (idx < 135168) {
    // src: W3[k][c], c = i*33 + jc  (jc=32 -> W3 bias col, becomes tile 32)
    int k = idx / 1056, c = idx % 1056;
    int i = c / 33, jc = c % 33;
    int ks = k >> 4, hi = (k >> 3) & 1, jj = k & 7;
    int lane = hi * 32 + i;
    Wg3[((jc * 8 + ks) * 64 + lane) * 8 + jj] = f2bf(W3[idx]);
  }
  if (idx < 16384) {
    // W2f (16x16x32 B-frags for the prologue, unchanged layout)
    int k = idx >> 7, n = idx & 127;
    int ks = k >> 5, kr = k & 31;
    int nt = n >> 4, low = n & 15;
    int l = ((kr >> 3) << 4) + low;
    int jj = k & 7;
    W2f[((ks * 8 + nt) * 64 + l) * 8 + jj] = f2bf(W2[idx]);
  }
  if (idx < 1056) {
    // b3t[jc*32 + i] = b3[i*33 + jc]  (per-tile C-init values, f32)
    int i = idx / 33, jc = idx % 33;
    b3t[jc * 32 + i] = b3[idx];
  }
}

// ---------------- fused main kernel ----------------
// 256 threads (4 waves), 256 edges/block; wave w owns edges [B0+w*64, B0+w*64+64).
// LDS (overlapped phases):
//   prologue: h2n u16[64][136] @0 (17408), h1c u16[32][136] @17408 (8704)
//   G-loop:   vt f32[33][260] @0 (34320)
__global__ __launch_bounds__(256) void fnn_fused(
    const float* __restrict__ pos_i, const float* __restrict__ pos_j,
    const float* __restrict__ vj, const float* __restrict__ W1,
    const float* __restrict__ b1, const float* __restrict__ b2,
    const unsigned short* __restrict__ W2f, const unsigned short* __restrict__ Wg3,
    const float* __restrict__ b3t,
    float* __restrict__ out) {
  __shared__ __attribute__((aligned(16))) char smem[34320];
  float* vt = (float*)smem;                                  // [33][260], G-loop phase
  unsigned short* h2n = (unsigned short*)smem;               // [64][136], prologue phase
  unsigned short* h1c = (unsigned short*)(smem + 17408);     // [32][136], prologue phase

  const int tid = threadIdx.x;
  const int w = tid >> 6, lane = tid & 63, q = lane >> 4, ln = lane & 15;
  const int hi = lane >> 5, i31 = lane & 31;
  const int B0 = blockIdx.x * EPB;

  // --- W1/b1 register slice: thread owns 8 hidden cols for stage 1 ---
  const int hh0 = (tid & 15) * 8;
  float w1r[4][8], b1r[8];
#pragma unroll
  for (int d = 0; d < 4; ++d)
#pragma unroll
    for (int u = 0; u < 8; ++u) w1r[d][u] = W1[d * 128 + hh0 + u];
#pragma unroll
  for (int u = 0; u < 8; ++u) b1r[u] = b1[hh0 + u];

  // --- stages 1+2 per quarter (64 edges), extract A-frags to registers ---
  // af[m][ks] = 32x32x16 A-frag: row = lane&31 (edge m*32+row), k = ks*16+(lane>>5)*8+jj
  s8v af[2][8];
  for (int qtr = 0; qtr < 4; ++qtr) {
    for (int cb = 0; cb < 2; ++cb) {
#pragma unroll
      for (int half = 0; half < 2; ++half) {
        int ee = (tid >> 4) + half * 16;
        int eg = B0 + qtr * 64 + cb * 32 + ee;
        float2 pi = *(const float2*)(pos_i + (size_t)eg * 2);
        float2 pj = *(const float2*)(pos_j + (size_t)eg * 2);
        s8v hv;
#pragma unroll
        for (int u = 0; u < 8; ++u) {
          float o = b1r[u] + pi.x * w1r[0][u] + pi.y * w1r[1][u] +
                    pj.x * w1r[2][u] + pj.y * w1r[3][u];
          hv[u] = (short)f2bf(fmaxf(o, 0.f));
        }
        *(s8v*)&h1c[ee * 136 + hh0] = hv;
      }
      __syncthreads();
#pragma unroll
      for (int s = 0; s < 4; ++s) {
        int tt = w * 4 + s, mt = tt >> 3, nt = tt & 7;
        f32x4 a4 = {0.f, 0.f, 0.f, 0.f};
#pragma unroll
        for (int ks = 0; ks < 4; ++ks) {
          s8v afr = *(const s8v*)&h1c[(mt * 16 + ln) * 136 + ks * 32 + q * 8];
          s8v bfr = *(const s8v*)(W2f + ((ks * 8 + nt) * 64 + lane) * 8);
          a4 = __builtin_amdgcn_mfma_f32_16x16x32_bf16(afr, bfr, a4, 0, 0, 0);
        }
        float b2v = b2[nt * 16 + ln];
        int eb = cb * 32 + mt * 16 + q * 4;
        int kc = nt * 16 + ln;
#pragma unroll
        for (int r = 0; r < 4; ++r)
          h2n[(eb + r) * 136 + kc] = f2bf(fmaxf(a4[r] + b2v, 0.f));
      }
      __syncthreads();
    }
    if (w == qtr) {
#pragma unroll
      for (int m = 0; m < 2; ++m)
#pragma unroll
        for (int ks = 0; ks < 8; ++ks)
          af[m][ks] = *(const s8v*)&h2n[(m * 32 + i31) * 136 + ks * 16 + hi * 8];
    }
    __syncthreads();   // last cross-wave dep: h2n reads drained before vt overwrite
  }

  // --- prime B tile 0 (two half-tile register buffers) while vt is being built ---
  s8v bfA[4], bfB[4];
#pragma unroll
  for (int t = 0; t < 4; ++t) bfA[t] = *(const s8v*)(Wg3 + ((0 * 8 + t) * 64 + lane) * 8);
#pragma unroll
  for (int t = 0; t < 4; ++t) bfB[t] = *(const s8v*)(Wg3 + ((0 * 8 + 4 + t) * 64 + lane) * 8);

  // --- build vt: vt[j][e] = v[e,j] (f32), row 32 = 1.0 (overwrites h1c/h2n region) ---
  // Wave w writes ONLY columns [w*64, w*64+64) and reads ONLY those columns in the
  // G-loop -> no cross-wave dependency -> NO barrier needed from here on.
  {
    const float* vrow = vj + (size_t)(B0 + tid) * 32;
#pragma unroll
    for (int j4 = 0; j4 < 8; ++j4) {
      float4 vv = *(const float4*)(vrow + j4 * 4);
      vt[(j4 * 4 + 0) * 260 + tid] = vv.x;
      vt[(j4 * 4 + 1) * 260 + tid] = vv.y;
      vt[(j4 * 4 + 2) * 260 + tid] = vv.z;
      vt[(j4 * 4 + 3) * 260 + tid] = vv.w;
    }
    vt[32 * 260 + tid] = 1.0f;
  }

  // --- G-loop: 33 j-tiles (32 cols each), zero barriers, half-tile ping-pong prefetch.
  //     Per tile: C-init = b3t broadcast; 16 MFMA (2 m-chains interleaved);
  //     epilogue oa += v[e,j] * C.
  f32x16 oa0, oa1;
#pragma unroll
  for (int r = 0; r < 16; ++r) { oa0[r] = 0.f; oa1[r] = 0.f; }

#pragma unroll 1
  for (int j = 0; j < 33; ++j) {
    float ci = b3t[j * 32 + i31];
    f32x16 c0, c1;
#pragma unroll
    for (int r = 0; r < 16; ++r) { c0[r] = ci; c1[r] = ci; }
#pragma unroll
    for (int ks = 0; ks < 4; ++ks) {
      c0 = __builtin_amdgcn_mfma_f32_32x32x16_bf16(af[0][ks], bfA[ks], c0, 0, 0, 0);
      c1 = __builtin_amdgcn_mfma_f32_32x32x16_bf16(af[1][ks], bfA[ks], c1, 0, 0, 0);
    }
#pragma unroll
    for (int t = 0; t < 4; ++t)   // prefetch next tile half-0 (j=32 -> W2f pad, unused)
      bfA[t] = *(const s8v*)(Wg3 + (((j + 1) * 8 + t) * 64 + lane) * 8);
#pragma unroll
    for (int ks = 0; ks < 4; ++ks) {
      c0 = __builtin_amdgcn_mfma_f32_32x32x16_bf16(af[0][4 + ks], bfB[ks], c0, 0, 0, 0);
      c1 = __builtin_amdgcn_mfma_f32_32x32x16_bf16(af[1][4 + ks], bfB[ks], c1, 0, 0, 0);
    }
#pragma unroll
    for (int t = 0; t < 4; ++t)   // prefetch next tile half-1
      bfB[t] = *(const s8v*)(Wg3 + (((j + 1) * 8 + 4 + t) * 64 + lane) * 8);

    // epilogue: edge row = (reg&3) + 8*(reg>>2) + 4*hi (+ m*32 + w*64)
    const float* vp = vt + j * 260 + w * 64 + 4 * hi;
#pragma unroll
    for (int g = 0; g < 4; ++g) {
      f32x4 vv = *(const f32x4*)(vp + 8 * g);
#pragma unroll
      for (int rr = 0; rr < 4; ++rr) oa0[4 * g + rr] += vv[rr] * c0[4 * g + rr];
    }
#pragma unroll
    for (int g = 0; g < 4; ++g) {
      f32x4 vv = *(const f32x4*)(vp + 32 + 8 * g);
#pragma unroll
      for (int rr = 0; rr < 4; ++rr) oa1[4 * g + rr] += vv[rr] * c1[4 * g + rr];
    }
  }

  // --- epilogue: out[e,i] f32; lanes 0..31 -> row e, lanes 32..63 -> row e+4 ---
#pragma unroll
  for (int g = 0; g < 4; ++g)
#pragma unroll
    for (int rr = 0; rr < 4; ++rr) {
      int e = B0 + w * 64 + 8 * g + 4 * hi + rr;
      out[(size_t)e * 32 + i31] = oa0[4 * g + rr];
    }
#pragma unroll
  for (int g = 0; g < 4; ++g)
#pragma unroll
    for (int rr = 0; rr < 4; ++rr) {
      int e = B0 + w * 64 + 32 + 8 * g + 4 * hi + rr;
      out[(size_t)e * 32 + i31] = oa1[4 * g + rr];
    }
}

extern "C" void kernel_launch(void* const* d_in, const int* in_sizes, int n_in,
                              void* d_out, int out_size, void* d_ws, size_t ws_size,
                              hipStream_t stream) {
  const float* pos_i = (const float*)d_in[0];
  const float* pos_j = (const float*)d_in[1];
  const float* vj    = (const float*)d_in[2];
  const float* W1    = (const float*)d_in[3];
  const float* b1    = (const float*)d_in[4];
  const float* W2    = (const float*)d_in[5];
  const float* b2    = (const float*)d_in[6];
  const float* W3    = (const float*)d_in[7];
  const float* b3    = (const float*)d_in[8];
  float* outp = (float*)d_out;

  float*          b3t = (float*)d_ws;                                   // 4224 B
  unsigned short* Wg3 = (unsigned short*)((char*)d_ws + 4224);          // 270336 B
  unsigned short* W2f = (unsigned short*)((char*)d_ws + 274560);        // 32768 B

  prep_pack<<<528, 256, 0, stream>>>(W2, W3, b3, b3t, Wg3, W2f);
  fnn_fused<<<NBLK, 256, 0, stream>>>(pos_i, pos_j, vj, W1, b1, b2, W2f, Wg3, b3t, outp);
}

// Round 12
// 235.229 us; speedup vs baseline: 1.7585x; 1.0361x over previous
//
#include <hip/hip_runtime.h>

// out[e,i] = sum_j mat[e,i,j] v[e,j] + bias[e,i],  [mat|bias] = MLP(pos).reshape(32,33)
// Round-13: INSTRUMENTATION round — double-G-loop ablation on the r5 base (105.6us,
// VGPR 120, zero spill). Five rounds of G-loop restructuring moved nothing; the cycle
// model under-predicts 3-4x; r11 showed wall scales ~linearly with waves/SIMD
// (1 wave=166us, 2 waves=105us) -> latency-bound. Before optimizing further we need
// the prologue vs G-loop split. This kernel runs the G-loop TWICE: pass 1 results
// kept live via asm volatile (prevent DCE) then discarded; oa re-initialized; pass 2
// is the real one. dur = P + 2*T_G -> delta vs 105.6 == T_G.
// Decision: dur>=165 -> G-dominant (attack G latency/occupancy);
//           dur<=145 -> prologue-dominant (~65us!) -> split/restructure prologue.
//   P[e, col] = h2[e,0:128] @ Wpack[0:128, col]   (col = j*32+i; W3-only)
//   out[e,i]  = sum_{col: i} vext[e,j] * P[e,col] + (b3 mini-GEMM)
// LDS = vt only (34320 B). ws: Wg2 @0 (270336), W2f @270336 (32768), b3f @303104
// (2048), b3c @305152 (128).

#define E_TOTAL 262144
#define EPB 256
#define NBLK (E_TOTAL / EPB)

typedef float f32x4 __attribute__((ext_vector_type(4)));
typedef short s8v  __attribute__((ext_vector_type(8)));

__device__ __forceinline__ unsigned short f2bf(float x) {
  unsigned u = __float_as_uint(x);
  u += 0x7fffu + ((u >> 16) & 1u);
  return (unsigned short)(u >> 16);
}

// ---------------- prep: pack W2/W3/b3 into MFMA B-fragment order ----------------
// Coalesced f32 reads, scattered bf16 writes (r7 version, verified passing).
__global__ void prep_pack(const float* __restrict__ W2, const float* __restrict__ W3,
                          const float* __restrict__ b3,
                          unsigned short* __restrict__ Wg2, unsigned short* __restrict__ W2f,
                          unsigned short* __restrict__ b3f, float* __restrict__ b3c) {
  int idx = blockIdx.x * 256 + threadIdx.x;   // 528 blocks cover 135168
  if (idx < 135168) {
    int k = idx / 1056, c = idx % 1056;
    int i = c / 33, jc = c % 33;
    int col = jc * 32 + i;                    // Wg2 col = j*32 + i
    int nnt = col >> 4, low = col & 15;
    int nn = (nnt & 1) ? (33 + (nnt >> 1)) : (nnt >> 1);   // permuted tile order
    int ks = k >> 5, kr = k & 31;
    int lane = ((kr >> 3) << 4) + low;
    int jj = k & 7;
    Wg2[((nn * 4 + ks) * 64 + lane) * 8 + jj] = f2bf(W3[idx]);
  }
  if (idx < 16384) {
    int k = idx >> 7, n = idx & 127;
    int ks = k >> 5, kr = k & 31;
    int nt = n >> 4, low = n & 15;
    int l = ((kr >> 3) << 4) + low;
    int jj = k & 7;
    W2f[((ks * 8 + nt) * 64 + l) * 8 + jj] = f2bf(W2[idx]);
  }
  if (idx < 1024) {
    int jj = idx & 7, lane = (idx >> 3) & 63, ih = idx >> 9;
    int j = ((lane >> 4) << 3) + jj, i = ih * 16 + (lane & 15);
    b3f[idx] = f2bf(b3[i * 33 + j]);
  }
  if (idx < 32) b3c[idx] = b3[idx * 33 + 32];
}

// ---------------- G-loop helpers (register-resident B, direct from L2) ----------------
__device__ __forceinline__ void tile_load(s8v (&dst)[4], const unsigned short* __restrict__ Wg2,
                                          int n, int lane) {
  const s8v* src = (const s8v*)(Wg2 + (size_t)n * 2048 + lane * 8);
#pragma unroll
  for (int ks = 0; ks < 4; ++ks) dst[ks] = src[ks * 64];
}

template <int IH>
__device__ __forceinline__ void tile_compute(const s8v (&bf)[4], const float* __restrict__ vt,
                                             int j, int eoff,
                                             const s8v (&af)[4][4], float (&oa)[2][4][4]) {
  const f32x4 zero4 = {0.f, 0.f, 0.f, 0.f};
  const float* vp = vt + j * 260 + eoff;
#pragma unroll
  for (int m = 0; m < 4; ++m) {
    f32x4 p = __builtin_amdgcn_mfma_f32_16x16x32_bf16(af[m][0], bf[0], zero4, 0, 0, 0);
#pragma unroll
    for (int ks = 1; ks < 4; ++ks)
      p = __builtin_amdgcn_mfma_f32_16x16x32_bf16(af[m][ks], bf[ks], p, 0, 0, 0);
    f32x4 vv = *(const f32x4*)(vp + m * 16);
#pragma unroll
    for (int r = 0; r < 4; ++r) oa[IH][m][r] += vv[r] * p[r];
  }
}

// ---------------- fused main kernel ----------------
// 256 threads (4 waves), 256 edges/block; wave w owns edges [B0+w*64, B0+w*64+64).
// LDS (overlapped phases):
//   prologue: h2n u16[64][136] @0 (17408), h1c u16[32][136] @17408 (8704)
//   G-loop:   vt f32[33][260] @0 (34320)
__global__ __launch_bounds__(256, 2) void fnn_fused(
    const float* __restrict__ pos_i, const float* __restrict__ pos_j,
    const float* __restrict__ vj, const float* __restrict__ W1,
    const float* __restrict__ b1, const float* __restrict__ b2,
    const unsigned short* __restrict__ W2f, const unsigned short* __restrict__ Wg2,
    const unsigned short* __restrict__ b3f, const float* __restrict__ b3c,
    float* __restrict__ out) {
  __shared__ __attribute__((aligned(16))) char smem[34320];
  float* vt = (float*)smem;                                  // [33][260], G-loop phase
  unsigned short* h2n = (unsigned short*)smem;               // [64][136], prologue phase
  unsigned short* h1c = (unsigned short*)(smem + 17408);     // [32][136], prologue phase

  const int tid = threadIdx.x;
  const int w = tid >> 6, lane = tid & 63, q = lane >> 4, ln = lane & 15;
  const int B0 = blockIdx.x * EPB;
  const int eoff = w * 64 + q * 4;

  // --- out-acc init via b3 mini-GEMM: oa[ih][m][r] = sum_j v[e,j] b3[i*33+j] + b3[i*33+32] ---
  float oa[2][4][4];
  {
    s8v av[4];
#pragma unroll
    for (int m = 0; m < 4; ++m) {
      int e = B0 + w * 64 + m * 16 + ln;
      const float4 va = *(const float4*)(vj + (size_t)e * 32 + q * 8);
      const float4 vb = *(const float4*)(vj + (size_t)e * 32 + q * 8 + 4);
      s8v t;
      t[0] = (short)f2bf(va.x); t[1] = (short)f2bf(va.y);
      t[2] = (short)f2bf(va.z); t[3] = (short)f2bf(va.w);
      t[4] = (short)f2bf(vb.x); t[5] = (short)f2bf(vb.y);
      t[6] = (short)f2bf(vb.z); t[7] = (short)f2bf(vb.w);
      av[m] = t;
    }
#pragma unroll
    for (int ih = 0; ih < 2; ++ih) {
      s8v b3fr = *(const s8v*)(b3f + (ih * 64 + lane) * 8);
      float cbv = b3c[ih * 16 + ln];
      f32x4 ci = {cbv, cbv, cbv, cbv};
#pragma unroll
      for (int m = 0; m < 4; ++m) {
        f32x4 p = __builtin_amdgcn_mfma_f32_16x16x32_bf16(av[m], b3fr, ci, 0, 0, 0);
#pragma unroll
        for (int r = 0; r < 4; ++r) oa[ih][m][r] = p[r];
      }
    }
  }

  // --- W1/b1 register slice: thread owns 8 hidden cols for stage 1 ---
  const int hh0 = (tid & 15) * 8;
  float w1r[4][8], b1r[8];
#pragma unroll
  for (int d = 0; d < 4; ++d)
#pragma unroll
    for (int u = 0; u < 8; ++u) w1r[d][u] = W1[d * 128 + hh0 + u];
#pragma unroll
  for (int u = 0; u < 8; ++u) b1r[u] = b1[hh0 + u];

  // --- stages 1+2 per quarter (64 edges), extract A-frags to registers ---
  s8v af[4][4];
  for (int qtr = 0; qtr < 4; ++qtr) {
    for (int cb = 0; cb < 2; ++cb) {
#pragma unroll
      for (int half = 0; half < 2; ++half) {
        int ee = (tid >> 4) + half * 16;
        int eg = B0 + qtr * 64 + cb * 32 + ee;
        float2 pi = *(const float2*)(pos_i + (size_t)eg * 2);
        float2 pj = *(const float2*)(pos_j + (size_t)eg * 2);
        s8v hv;
#pragma unroll
        for (int u = 0; u < 8; ++u) {
          float o = b1r[u] + pi.x * w1r[0][u] + pi.y * w1r[1][u] +
                    pj.x * w1r[2][u] + pj.y * w1r[3][u];
          hv[u] = (short)f2bf(fmaxf(o, 0.f));
        }
        *(s8v*)&h1c[ee * 136 + hh0] = hv;
      }
      __syncthreads();
#pragma unroll
      for (int s = 0; s < 4; ++s) {
        int tt = w * 4 + s, mt = tt >> 3, nt = tt & 7;
        f32x4 a4 = {0.f, 0.f, 0.f, 0.f};
#pragma unroll
        for (int ks = 0; ks < 4; ++ks) {
          s8v afr = *(const s8v*)&h1c[(mt * 16 + ln) * 136 + ks * 32 + q * 8];
          s8v bfr = *(const s8v*)(W2f + ((ks * 8 + nt) * 64 + lane) * 8);
          a4 = __builtin_amdgcn_mfma_f32_16x16x32_bf16(afr, bfr, a4, 0, 0, 0);
        }
        float b2v = b2[nt * 16 + ln];
        int eb = cb * 32 + mt * 16 + q * 4;
        int kc = nt * 16 + ln;
#pragma unroll
        for (int r = 0; r < 4; ++r)
          h2n[(eb + r) * 136 + kc] = f2bf(fmaxf(a4[r] + b2v, 0.f));
      }
      __syncthreads();
    }
    if (w == qtr) {
#pragma unroll
      for (int m = 0; m < 4; ++m)
#pragma unroll
        for (int ks = 0; ks < 4; ++ks)
          af[m][ks] = *(const s8v*)&h2n[(m * 16 + ln) * 136 + ks * 32 + q * 8];
    }
    __syncthreads();   // last cross-wave dep: h2n reads drained before vt overwrite
  }

  // --- prime B tile 0 while vt is being built ---
  s8v bf[4];
  tile_load(bf, Wg2, 0, lane);

  // --- build vt: vt[j][e] = v[e,j] (f32), row 32 = 1.0 (overwrites h1c/h2n region) ---
  {
    const float* vrow = vj + (size_t)(B0 + tid) * 32;
#pragma unroll
    for (int j4 = 0; j4 < 8; ++j4) {
      float4 vv = *(const float4*)(vrow + j4 * 4);
      vt[(j4 * 4 + 0) * 260 + tid] = vv.x;
      vt[(j4 * 4 + 1) * 260 + tid] = vv.y;
      vt[(j4 * 4 + 2) * 260 + tid] = vv.z;
      vt[(j4 * 4 + 3) * 260 + tid] = vv.w;
    }
    vt[32 * 260 + tid] = 1.0f;
  }

  // ================= PASS 1 (instrumentation; results discarded) =================
#pragma unroll 1
  for (int n = 0; n < 33; ++n) {
    tile_compute<0>(bf, vt, n, eoff, af, oa);
    tile_load(bf, Wg2, n + 1, lane);
  }
#pragma unroll 1
  for (int n = 33; n < 66; ++n) {
    tile_compute<1>(bf, vt, n - 33, eoff, af, oa);
    tile_load(bf, Wg2, n + 1, lane);
  }
  // keep pass-1 results live so the compiler cannot DCE the pass (rule #17)
#pragma unroll
  for (int ih = 0; ih < 2; ++ih)
#pragma unroll
    for (int m = 0; m < 4; ++m)
#pragma unroll
      for (int r = 0; r < 4; ++r) asm volatile("" ::"v"(oa[ih][m][r]));

  // --- re-init oa (low-pressure variant: af is live here, avoid av[4] array) ---
  {
    s8v b3fr0 = *(const s8v*)(b3f + (0 * 64 + lane) * 8);
    s8v b3fr1 = *(const s8v*)(b3f + (1 * 64 + lane) * 8);
    float cb0 = b3c[ln], cb1 = b3c[16 + ln];
    f32x4 ci0 = {cb0, cb0, cb0, cb0}, ci1 = {cb1, cb1, cb1, cb1};
#pragma unroll
    for (int m = 0; m < 4; ++m) {
      int e = B0 + w * 64 + m * 16 + ln;
      const float4 va = *(const float4*)(vj + (size_t)e * 32 + q * 8);
      const float4 vb = *(const float4*)(vj + (size_t)e * 32 + q * 8 + 4);
      s8v t;
      t[0] = (short)f2bf(va.x); t[1] = (short)f2bf(va.y);
      t[2] = (short)f2bf(va.z); t[3] = (short)f2bf(va.w);
      t[4] = (short)f2bf(vb.x); t[5] = (short)f2bf(vb.y);
      t[6] = (short)f2bf(vb.z); t[7] = (short)f2bf(vb.w);
      f32x4 p0 = __builtin_amdgcn_mfma_f32_16x16x32_bf16(t, b3fr0, ci0, 0, 0, 0);
      f32x4 p1 = __builtin_amdgcn_mfma_f32_16x16x32_bf16(t, b3fr1, ci1, 0, 0, 0);
#pragma unroll
      for (int r = 0; r < 4; ++r) { oa[0][m][r] = p0[r]; oa[1][m][r] = p1[r]; }
    }
  }
  tile_load(bf, Wg2, 0, lane);   // re-prime

  // ================= PASS 2 (real) =================
#pragma unroll 1
  for (int n = 0; n < 33; ++n) {
    tile_compute<0>(bf, vt, n, eoff, af, oa);
    tile_load(bf, Wg2, n + 1, lane);
  }
#pragma unroll 1
  for (int n = 33; n < 66; ++n) {
    tile_compute<1>(bf, vt, n - 33, eoff, af, oa);
    tile_load(bf, Wg2, n + 1, lane);
  }

  // --- epilogue: out[e,i] f32 ---
#pragma unroll
  for (int m = 0; m < 4; ++m)
#pragma unroll
    for (int ih = 0; ih < 2; ++ih)
#pragma unroll
      for (int r = 0; r < 4; ++r) {
        int e = B0 + w * 64 + m * 16 + q * 4 + r;
        out[(size_t)e * 32 + ih * 16 + ln] = oa[ih][m][r];
      }
}

extern "C" void kernel_launch(void* const* d_in, const int* in_sizes, int n_in,
                              void* d_out, int out_size, void* d_ws, size_t ws_size,
                              hipStream_t stream) {
  const float* pos_i = (const float*)d_in[0];
  const float* pos_j = (const float*)d_in[1];
  const float* vj    = (const float*)d_in[2];
  const float* W1    = (const float*)d_in[3];
  const float* b1    = (const float*)d_in[4];
  const float* W2    = (const float*)d_in[5];
  const float* b2    = (const float*)d_in[6];
  const float* W3    = (const float*)d_in[7];
  const float* b3    = (const float*)d_in[8];
  float* outp = (float*)d_out;

  unsigned short* Wg2 = (unsigned short*)d_ws;
  unsigned short* W2f = (unsigned short*)((char*)d_ws + 270336);
  unsigned short* b3f = (unsigned short*)((char*)d_ws + 303104);
  float*          b3c = (float*)((char*)d_ws + 305152);

  prep_pack<<<528, 256, 0, stream>>>(W2, W3, b3, Wg2, W2f, b3f, b3c);
  fnn_fused<<<NBLK, 256, 0, stream>>>(pos_i, pos_j, vj, W1, b1, b2, W2f, Wg2, b3f, b3c, outp);
}

// Round 13
// 177.529 us; speedup vs baseline: 2.3300x; 1.3250x over previous
//
#include <hip/hip_runtime.h>

// out[e,i] = sum_j mat[e,i,j] v[e,j] + bias[e,i],  [mat|bias] = MLP(pos).reshape(32,33)
// Round-14: prologue restructure. r13 ablation: T_G=52.5us, P=53us -> the prologue
// (1/8 of FLOPs) costs as much as the G-loop. Causes: 20 barriers, 128 re-fetched
// W2f global loads/wave (same data every cb round), 32-edge micro-phases.
// Fix (G-loop/regs identical to r5 = 120 VGPR no-spill):
//   - W2f staged to LDS once via global_load_lds -> stage-2 B-frags are ds_reads
//   - 64-edge phases, wave w owns tile-row mt=w, 8 nt each -> 9 barriers total
//   - b2 hoisted to b2r[8]
// LDS 67584 B (prologue: h1c[64][136] @0, h2n[64][136] @17408, W2L @34816;
// G-loop: vt[33][260] @0 overlays h1c+h2n). 2 blocks/CU (reg-capped anyway).
//   P[e, col] = h2[e,0:128] @ Wpack[0:128, col]   (col = j*32+i; W3-only)
//   out[e,i]  = sum_{col: i} vext[e,j] * P[e,col] + (b3 mini-GEMM)
// ws: Wg2 @0 (270336), W2f @270336 (32768), b3f @303104 (2048), b3c @305152 (128).

#define E_TOTAL 262144
#define EPB 256
#define NBLK (E_TOTAL / EPB)

typedef float f32x4 __attribute__((ext_vector_type(4)));
typedef short s8v  __attribute__((ext_vector_type(8)));
typedef unsigned int u32;

__device__ __forceinline__ unsigned short f2bf(float x) {
  unsigned u = __float_as_uint(x);
  u += 0x7fffu + ((u >> 16) & 1u);
  return (unsigned short)(u >> 16);
}

__device__ __forceinline__ void ld16_g2l(const void* g, void* l) {
  __builtin_amdgcn_global_load_lds((const __attribute__((address_space(1))) u32*)g,
                                   (__attribute__((address_space(3))) u32*)l, 16, 0, 0);
}

// ---------------- prep: pack W2/W3/b3 into MFMA B-fragment order ----------------
// Coalesced f32 reads, scattered bf16 writes (r7 version, verified).
__global__ void prep_pack(const float* __restrict__ W2, const float* __restrict__ W3,
                          const float* __restrict__ b3,
                          unsigned short* __restrict__ Wg2, unsigned short* __restrict__ W2f,
                          unsigned short* __restrict__ b3f, float* __restrict__ b3c) {
  int idx = blockIdx.x * 256 + threadIdx.x;   // 528 blocks cover 135168
  if (idx < 135168) {
    int k = idx / 1056, c = idx % 1056;
    int i = c / 33, jc = c % 33;
    int col = jc * 32 + i;                    // Wg2 col = j*32 + i
    int nnt = col >> 4, low = col & 15;
    int nn = (nnt & 1) ? (33 + (nnt >> 1)) : (nnt >> 1);   // permuted tile order
    int ks = k >> 5, kr = k & 31;
    int lane = ((kr >> 3) << 4) + low;
    int jj = k & 7;
    Wg2[((nn * 4 + ks) * 64 + lane) * 8 + jj] = f2bf(W3[idx]);
  }
  if (idx < 16384) {
    int k = idx >> 7, n = idx & 127;
    int ks = k >> 5, kr = k & 31;
    int nt = n >> 4, low = n & 15;
    int l = ((kr >> 3) << 4) + low;
    int jj = k & 7;
    W2f[((ks * 8 + nt) * 64 + l) * 8 + jj] = f2bf(W2[idx]);
  }
  if (idx < 1024) {
    int jj = idx & 7, lane = (idx >> 3) & 63, ih = idx >> 9;
    int j = ((lane >> 4) << 3) + jj, i = ih * 16 + (lane & 15);
    b3f[idx] = f2bf(b3[i * 33 + j]);
  }
  if (idx < 32) b3c[idx] = b3[idx * 33 + 32];
}

// ---------------- G-loop helpers (register-resident B, direct from L2) ----------------
__device__ __forceinline__ void tile_load(s8v (&dst)[4], const unsigned short* __restrict__ Wg2,
                                          int n, int lane) {
  const s8v* src = (const s8v*)(Wg2 + (size_t)n * 2048 + lane * 8);
#pragma unroll
  for (int ks = 0; ks < 4; ++ks) dst[ks] = src[ks * 64];
}

template <int IH>
__device__ __forceinline__ void tile_compute(const s8v (&bf)[4], const float* __restrict__ vt,
                                             int j, int eoff,
                                             const s8v (&af)[4][4], float (&oa)[2][4][4]) {
  const f32x4 zero4 = {0.f, 0.f, 0.f, 0.f};
  const float* vp = vt + j * 260 + eoff;
#pragma unroll
  for (int m = 0; m < 4; ++m) {
    f32x4 p = __builtin_amdgcn_mfma_f32_16x16x32_bf16(af[m][0], bf[0], zero4, 0, 0, 0);
#pragma unroll
    for (int ks = 1; ks < 4; ++ks)
      p = __builtin_amdgcn_mfma_f32_16x16x32_bf16(af[m][ks], bf[ks], p, 0, 0, 0);
    f32x4 vv = *(const f32x4*)(vp + m * 16);
#pragma unroll
    for (int r = 0; r < 4; ++r) oa[IH][m][r] += vv[r] * p[r];
  }
}

// ---------------- fused main kernel ----------------
// 256 threads (4 waves), 256 edges/block; wave w owns edges [B0+w*64, B0+w*64+64).
// LDS: prologue h1c u16[64][136] @0, h2n u16[64][136] @17408, W2L u16[16384] @34816;
//      G-loop vt f32[33][260] @0 (overlays h1c+h2n). Total 67584 B.
__global__ __launch_bounds__(256, 2) void fnn_fused(
    const float* __restrict__ pos_i, const float* __restrict__ pos_j,
    const float* __restrict__ vj, const float* __restrict__ W1,
    const float* __restrict__ b1, const float* __restrict__ b2,
    const unsigned short* __restrict__ W2f, const unsigned short* __restrict__ Wg2,
    const unsigned short* __restrict__ b3f, const float* __restrict__ b3c,
    float* __restrict__ out) {
  __shared__ __attribute__((aligned(16))) char smem[67584];
  float* vt = (float*)smem;                                  // [33][260], G-loop phase
  unsigned short* h1c = (unsigned short*)smem;               // [64][136], prologue
  unsigned short* h2n = (unsigned short*)(smem + 17408);     // [64][136], prologue
  unsigned short* W2L = (unsigned short*)(smem + 34816);     // [16384],   prologue

  const int tid = threadIdx.x;
  const int w = tid >> 6, lane = tid & 63, q = lane >> 4, ln = lane & 15;
  const int B0 = blockIdx.x * EPB;
  const int eoff = w * 64 + q * 4;

  // --- stage W2f -> LDS once (async, zero registers; drained by first barrier) ---
  {
    const unsigned short* src = W2f + tid * 8;
    char* dstb = smem + 34816 + w * 1024;   // wave-uniform base
#pragma unroll
    for (int cc = 0; cc < 8; ++cc)
      ld16_g2l(src + cc * 2048, dstb + cc * 4096);
  }

  // --- out-acc init via b3 mini-GEMM: oa[ih][m][r] = sum_j v[e,j] b3[i*33+j] + b3[i*33+32] ---
  float oa[2][4][4];
  {
    s8v av[4];
#pragma unroll
    for (int m = 0; m < 4; ++m) {
      int e = B0 + w * 64 + m * 16 + ln;
      const float4 va = *(const float4*)(vj + (size_t)e * 32 + q * 8);
      const float4 vb = *(const float4*)(vj + (size_t)e * 32 + q * 8 + 4);
      s8v t;
      t[0] = (short)f2bf(va.x); t[1] = (short)f2bf(va.y);
      t[2] = (short)f2bf(va.z); t[3] = (short)f2bf(va.w);
      t[4] = (short)f2bf(vb.x); t[5] = (short)f2bf(vb.y);
      t[6] = (short)f2bf(vb.z); t[7] = (short)f2bf(vb.w);
      av[m] = t;
    }
#pragma unroll
    for (int ih = 0; ih < 2; ++ih) {
      s8v b3fr = *(const s8v*)(b3f + (ih * 64 + lane) * 8);
      float cbv = b3c[ih * 16 + ln];
      f32x4 ci = {cbv, cbv, cbv, cbv};
#pragma unroll
      for (int m = 0; m < 4; ++m) {
        f32x4 p = __builtin_amdgcn_mfma_f32_16x16x32_bf16(av[m], b3fr, ci, 0, 0, 0);
#pragma unroll
        for (int r = 0; r < 4; ++r) oa[ih][m][r] = p[r];
      }
    }
  }

  // --- W1/b1/b2 register slices ---
  const int hh0 = (tid & 15) * 8;
  float w1r[4][8], b1r[8], b2r[8];
#pragma unroll
  for (int d = 0; d < 4; ++d)
#pragma unroll
    for (int u = 0; u < 8; ++u) w1r[d][u] = W1[d * 128 + hh0 + u];
#pragma unroll
  for (int u = 0; u < 8; ++u) b1r[u] = b1[hh0 + u];
#pragma unroll
  for (int s = 0; s < 8; ++s) b2r[s] = b2[s * 16 + ln];

  // --- stages 1+2 per quarter (64 edges/phase), 2 barriers/qtr ---
  s8v af[4][4];
  for (int qtr = 0; qtr < 4; ++qtr) {
    // stage 1: all 64 edges of this quarter; thread computes 4 edges x 8 cols
#pragma unroll
    for (int half = 0; half < 4; ++half) {
      int ee = (tid >> 4) + half * 16;
      int eg = B0 + qtr * 64 + ee;
      float2 pi = *(const float2*)(pos_i + (size_t)eg * 2);
      float2 pj = *(const float2*)(pos_j + (size_t)eg * 2);
      s8v hv;
#pragma unroll
      for (int u = 0; u < 8; ++u) {
        float o = b1r[u] + pi.x * w1r[0][u] + pi.y * w1r[1][u] +
                  pj.x * w1r[2][u] + pj.y * w1r[3][u];
        hv[u] = (short)f2bf(fmaxf(o, 0.f));
      }
      *(s8v*)&h1c[ee * 136 + hh0] = hv;
    }
    __syncthreads();   // h1c ready (also drains W2L staging on qtr 0)

    // stage 2: wave w owns tile-row mt=w (edges w*16..w*16+16), iterates 8 nt
#pragma unroll
    for (int s = 0; s < 8; ++s) {
      f32x4 a4 = {0.f, 0.f, 0.f, 0.f};
#pragma unroll
      for (int ks = 0; ks < 4; ++ks) {
        s8v afr = *(const s8v*)&h1c[(w * 16 + ln) * 136 + ks * 32 + q * 8];
        s8v bfr = *(const s8v*)&W2L[((ks * 8 + s) * 64 + lane) * 8];
        a4 = __builtin_amdgcn_mfma_f32_16x16x32_bf16(afr, bfr, a4, 0, 0, 0);
      }
      int eb = w * 16 + q * 4;
      int kc = s * 16 + ln;
#pragma unroll
      for (int r = 0; r < 4; ++r)
        h2n[(eb + r) * 136 + kc] = f2bf(fmaxf(a4[r] + b2r[s], 0.f));
    }
    __syncthreads();   // h2n ready

    if (w == qtr) {
#pragma unroll
      for (int m = 0; m < 4; ++m)
#pragma unroll
        for (int ks = 0; ks < 4; ++ks)
          af[m][ks] = *(const s8v*)&h2n[(m * 16 + ln) * 136 + ks * 32 + q * 8];
    }
    // extraction reads h2n; next qtr's stage-2 writes are fenced by its own
    // post-stage-1 barrier -> no extra barrier needed here.
  }
  __syncthreads();   // final: extraction drained before vt overwrites h1c/h2n

  // --- prime B tile 0 while vt is being built ---
  s8v bf[4];
  tile_load(bf, Wg2, 0, lane);

  // --- build vt: vt[j][e] = v[e,j] (f32), row 32 = 1.0 ---
  // Wave w writes/reads ONLY columns [w*64, w*64+64) -> no barrier from here on.
  {
    const float* vrow = vj + (size_t)(B0 + tid) * 32;
#pragma unroll
    for (int j4 = 0; j4 < 8; ++j4) {
      float4 vv = *(const float4*)(vrow + j4 * 4);
      vt[(j4 * 4 + 0) * 260 + tid] = vv.x;
      vt[(j4 * 4 + 1) * 260 + tid] = vv.y;
      vt[(j4 * 4 + 2) * 260 + tid] = vv.z;
      vt[(j4 * 4 + 3) * 260 + tid] = vv.w;
    }
    vt[32 * 260 + tid] = 1.0f;
  }

  // --- G-loop: 66 flat tiles, depth-1 prefetch, zero barriers (r5 structure) ---
#pragma unroll 1
  for (int n = 0; n < 33; ++n) {
    tile_compute<0>(bf, vt, n, eoff, af, oa);
    tile_load(bf, Wg2, n + 1, lane);
  }
#pragma unroll 1
  for (int n = 33; n < 66; ++n) {
    tile_compute<1>(bf, vt, n - 33, eoff, af, oa);
    tile_load(bf, Wg2, n + 1, lane);   // n=65 -> tile 66 = pad overread (W2f region), unused
  }

  // --- epilogue: out[e,i] f32 ---
#pragma unroll
  for (int m = 0; m < 4; ++m)
#pragma unroll
    for (int ih = 0; ih < 2; ++ih)
#pragma unroll
      for (int r = 0; r < 4; ++r) {
        int e = B0 + w * 64 + m * 16 + q * 4 + r;
        out[(size_t)e * 32 + ih * 16 + ln] = oa[ih][m][r];
      }
}

extern "C" void kernel_launch(void* const* d_in, const int* in_sizes, int n_in,
                              void* d_out, int out_size, void* d_ws, size_t ws_size,
                              hipStream_t stream) {
  const float* pos_i = (const float*)d_in[0];
  const float* pos_j = (const float*)d_in[1];
  const float* vj    = (const float*)d_in[2];
  const float* W1    = (const float*)d_in[3];
  const float* b1    = (const float*)d_in[4];
  const float* W2    = (const float*)d_in[5];
  const float* b2    = (const float*)d_in[6];
  const float* W3    = (const float*)d_in[7];
  const float* b3    = (const float*)d_in[8];
  float* outp = (float*)d_out;

  unsigned short* Wg2 = (unsigned short*)d_ws;
  unsigned short* W2f = (unsigned short*)((char*)d_ws + 270336);
  unsigned short* b3f = (unsigned short*)((char*)d_ws + 303104);
  float*          b3c = (float*)((char*)d_ws + 305152);

  prep_pack<<<528, 256, 0, stream>>>(W2, W3, b3, Wg2, W2f, b3f, b3c);
  fnn_fused<<<NBLK, 256, 0, stream>>>(pos_i, pos_j, vj, W1, b1, b2, W2f, Wg2, b3f, b3c, outp);
}